// Round 4
// baseline (197.838 us; speedup 1.0000x reference)
//
#include <hip/hip_runtime.h>

#define NEG (-1e9f)
constexpr int NCLS   = 21;
constexpr int NBOX   = 8732;
constexpr int MAXOUT = 5;
constexpr int CAP    = NBOX;          // worst-case candidates per batch
constexpr float IOU_THR  = 0.5f;
constexpr float CONF_THR = 0.5f;

// ---------------------------------------------------------------------------
// Phase 1: decode + softmax max/argmax + candidate compaction.
// Staging: async global->LDS (global_load_lds, 16B/lane). One block = 256
// boxes = 25600 B = 25 chunk-instructions of 1 KB (64 lanes x 16 B), spread
// over the 4 waves. Lane-contiguous global addresses -> perfectly coalesced;
// no VGPR round-trip; fire-and-forget until the __syncthreads (which drains
// vmcnt). 6 blocks/CU resident (25.6 KB LDS) overlap barrier-wait of one
// block with compute of the others.
// Per-thread LDS read at stride 25 floats: odd stride -> exactly 2-way lane
// aliasing on 32 banks, which is free.
// Only boxes with (argmax class != 0 && score > CONF_THR) can ever appear in
// the output: a selection with score <= 0.5 zeroes that slot and all later
// slots, so its suppression never matters. Hence exact NMS on the compacted
// candidate set. Arithmetic per box identical to reference (bit-exact).
// ---------------------------------------------------------------------------
__global__ __launch_bounds__(256) void decode_kernel(
        const float* __restrict__ logits,
        const float* __restrict__ dbox,
        float4* __restrict__ cand,
        int* __restrict__ cnt,
        int BN) {
    __shared__ float sl[256 * 25];          // 25600 B
    const int t    = threadIdx.x;
    const int wave = t >> 6;
    const int lane = t & 63;
    const long long blockBaseF = (long long)blockIdx.x * 6400;   // floats
    const long long totalF     = (long long)BN * 25;

    if (blockBaseF + 6400 <= totalF) {
        // fast path: 25 async 1KB chunks, chunk c issued by wave c%4
        const float* gbase = logits + blockBaseF;
#pragma unroll
        for (int c = 0; c < 25; c++) {
            if ((c & 3) == wave) {
                const float* gp = gbase + c * 256 + lane * 4;
                __builtin_amdgcn_global_load_lds(
                    (const __attribute__((address_space(1))) void*)gp,
                    (__attribute__((address_space(3))) void*)(sl + c * 256),
                    16, 0, 0);
            }
        }
    } else {
        // tail path (not hit for BN % 256 == 0): guarded strided loads
        for (int j = t; j < 6400; j += 256) {
            long long g = blockBaseF + j;
            sl[j] = (g < totalF) ? logits[g] : 0.f;
        }
    }
    __syncthreads();   // drains vmcnt(0) -> LDS staging complete

    const int i = blockIdx.x * 256 + t;
    if (i >= BN) return;
    const float* L = sl + t * 25;
    const int n = i % NBOX;
    const int b = i / NBOX;

    // decode (identical expression order to reference)
    float d0 = dbox[n * 4 + 0], d1 = dbox[n * 4 + 1];
    float d2 = dbox[n * 4 + 2], d3 = dbox[n * 4 + 3];
    float cy = (d2 + d0) * 0.5f;
    float cx = (d3 + d1) * 0.5f;
    float h  = d2 - d0;
    float w  = d3 - d1;
    float ncy = L[0] * h + cy;
    float ncx = L[1] * w + cx;
    float nh  = expf(L[2]) * h;
    float nw  = expf(L[3]) * w;
    float y1 = fminf(fmaxf(ncy - nh * 0.5f, 0.f), 1.f);
    float x1 = fminf(fmaxf(ncx - nw * 0.5f, 0.f), 1.f);
    float y2 = fminf(fmaxf(ncy + nh * 0.5f, 0.f), 1.f);
    float x2 = fminf(fmaxf(ncx + nw * 0.5f, 0.f), 1.f);

    // argmax(probs)==argmax(logits), first index on ties;
    // max prob = 1/sum(exp(x-max)), same accumulation order as reference
    float m = L[4];
    int am = 0;
#pragma unroll
    for (int j = 1; j < NCLS; j++) {
        float x = L[4 + j];
        if (x > m) { m = x; am = j; }
    }
    float sum = 0.f;
#pragma unroll
    for (int j = 0; j < NCLS; j++) sum += expf(L[4 + j] - m);
    float score = 1.0f / sum;

    if (am != 0 && score > CONF_THR) {
        int p = atomicAdd(&cnt[b], 1);
        if (p < CAP) {
            float4* c = cand + ((long long)b * CAP + p) * 2;
            c[0] = make_float4(y1, x1, y2, x2);
            c[1] = make_float4(score, (float)am, (float)n, 0.f);
        }
    }
}

// ---------------------------------------------------------------------------
// Phase 2: exact NMS over the candidate set. One block per batch element.
// Selection order: (score desc, original index asc) == jnp.argmax semantics.
// ---------------------------------------------------------------------------
__global__ __launch_bounds__(256) void nms_kernel(
        const float4* __restrict__ cand,
        const int* __restrict__ cnt,
        float* __restrict__ out) {
    const int b = blockIdx.x;
    const int t = threadIdx.x;
    __shared__ float s_sc[CAP];
    __shared__ float s_id[CAP];
    __shared__ float r_v[256];
    __shared__ float r_oid[256];
    __shared__ int   r_i[256];
    __shared__ float4 selbox_sh;

    const int M = min(cnt[b], CAP);
    const float4* cb = cand + (long long)b * CAP * 2;

    for (int i = t; i < M; i += 256) {
        float4 mrec = cb[i * 2 + 1];
        s_sc[i] = mrec.x;
        s_id[i] = mrec.z;
    }
    __syncthreads();

    for (int k = 0; k < MAXOUT; k++) {
        // block argmax, lexicographic (score desc, orig idx asc)
        float bv = -INFINITY, boid = 3.0e38f;
        int bi = -1;
        for (int i = t; i < M; i += 256) {
            float v = s_sc[i], oid = s_id[i];
            if (v > bv || (v == bv && oid < boid)) { bv = v; boid = oid; bi = i; }
        }
        r_v[t] = bv; r_oid[t] = boid; r_i[t] = bi;
        __syncthreads();
        for (int off = 128; off > 0; off >>= 1) {
            if (t < off) {
                float v2 = r_v[t + off];
                if (v2 > r_v[t] || (v2 == r_v[t] && r_oid[t + off] < r_oid[t])) {
                    r_v[t] = v2; r_oid[t] = r_oid[t + off]; r_i[t] = r_i[t + off];
                }
            }
            __syncthreads();
        }
        const int   sel = r_i[0];
        const float sc  = r_v[0];
        const bool valid = (sel >= 0) && (sc > CONF_THR);

        if (t == 0) {
            float* o = out + ((long long)b * MAXOUT + k) * 6;
            if (valid) {
                float4 bx = cb[sel * 2];
                float4 mm = cb[sel * 2 + 1];
                selbox_sh = bx;
                o[0] = bx.x; o[1] = bx.y; o[2] = bx.z; o[3] = bx.w;
                o[4] = mm.y; o[5] = sc;
            } else {
                o[0] = 0.f; o[1] = 0.f; o[2] = 0.f;
                o[3] = 0.f; o[4] = 0.f; o[5] = 0.f;
            }
        }
        __syncthreads();
        if (!valid) continue;  // block-uniform; later slots all zeros anyway

        // IoU suppression over candidates (reference formula, includes self)
        float4 sb = selbox_sh;
        float a1 = (sb.z - sb.x) * (sb.w - sb.y);
        for (int i = t; i < M; i += 256) {
            float4 c = cb[i * 2];
            float tly = fmaxf(sb.x, c.x);
            float tlx = fmaxf(sb.y, c.y);
            float bry = fminf(sb.z, c.z);
            float brx = fminf(sb.w, c.w);
            float wh0 = fmaxf(bry - tly, 0.f);
            float wh1 = fmaxf(brx - tlx, 0.f);
            float inter = wh0 * wh1;
            float a2 = (c.z - c.x) * (c.w - c.y);
            float iou = inter / (a1 + a2 - inter + 1e-12f);
            if (iou > IOU_THR) s_sc[i] = NEG;
        }
        __syncthreads();
    }
}

extern "C" void kernel_launch(void* const* d_in, const int* in_sizes, int n_in,
                              void* d_out, int out_size, void* d_ws, size_t ws_size,
                              hipStream_t stream) {
    const float* logits = (const float*)d_in[0];
    const float* dbox   = (const float*)d_in[1];
    float* out          = (float*)d_out;

    const int N  = in_sizes[1] / 4;           // 8732
    const int B  = in_sizes[0] / (N * 25);    // 128
    const int BN = B * N;

    // ws layout: [cnt: B ints][pad to 16B][cand: B*CAP*2 float4]
    int* cnt = (int*)d_ws;
    float4* cand = (float4*)((char*)d_ws + (((size_t)B * sizeof(int) + 15) & ~(size_t)15));

    hipMemsetAsync(cnt, 0, (size_t)B * sizeof(int), stream);
    decode_kernel<<<(BN + 255) / 256, 256, 0, stream>>>(logits, dbox, cand, cnt, BN);
    nms_kernel<<<B, 256, 0, stream>>>(cand, cnt, out);
}

// Round 5
// 194.752 us; speedup vs baseline: 1.0158x; 1.0158x over previous
//
#include <hip/hip_runtime.h>

#define NEG (-1e9f)
constexpr int NCLS   = 21;
constexpr int NBOX   = 8732;
constexpr int MAXOUT = 5;
constexpr int CAP    = NBOX;          // worst-case candidates per batch
constexpr float IOU_THR  = 0.5f;
constexpr float CONF_THR = 0.5f;

// ---------------------------------------------------------------------------
// Phase 1: decode + softmax max/argmax + candidate compaction.
// Wave-private pipelines, ZERO barriers: each 64-lane wave owns a 64-box /
// 6400 B LDS segment, stages it with 25 async global_load_lds chunks of
// 256 B (lane-contiguous -> coalesced), then waits only on ITS OWN vmcnt.
// 6 blocks/CU x 4 waves = 24 fully independent [issue -> wait -> compute]
// pipelines per CU that slip freely against each other -- the memory-level
// parallelism the barrier-coupled versions (R2-R4, all ~68 us) never had.
// LDS read stride 25 floats: odd stride -> 2-way lane aliasing (free).
// Only boxes with (argmax class != 0 && score > CONF_THR) can ever appear in
// the output (a selection with score <= 0.5 zeroes that slot and all later
// slots, so its suppression never matters) -> exact NMS on the compacted set.
// Per-box arithmetic identical to reference (bit-exact, absmax 0.0 in R1-R4).
// ---------------------------------------------------------------------------
__global__ __launch_bounds__(256) void decode_kernel(
        const float* __restrict__ logits,
        const float4* __restrict__ dbox4,
        float4* __restrict__ cand,
        int* __restrict__ cnt,
        int BN) {
    __shared__ float sl[4][64 * 25];        // 6400 B per wave, 25600 B total
    const int t    = threadIdx.x;
    const int wave = t >> 6;
    const int lane = t & 63;
    float* slw = sl[wave];

    const long long waveBox = ((long long)blockIdx.x * 4 + wave) * 64;
    if (waveBox >= BN) return;              // wave-uniform
    const long long gF     = waveBox * 25;  // float offset of this wave's slab
    const long long totalF = (long long)BN * 25;

    if (waveBox + 64 <= BN) {
        // fast path: 25 async 256B chunks (64 lanes x 4B), wave-private
        const float* gbase = logits + gF;
#pragma unroll
        for (int c = 0; c < 25; c++) {
            __builtin_amdgcn_global_load_lds(
                (const __attribute__((address_space(1))) void*)(gbase + c * 64 + lane),
                (__attribute__((address_space(3))) void*)(slw + c * 64),
                4, 0, 0);
        }
    } else {
        // tail (not hit when BN % 256 == 0): guarded strided scalar loads
        for (int j = lane; j < 64 * 25; j += 64) {
            long long g = gF + j;
            slw[j] = (g < totalF) ? logits[g] : 0.f;
        }
    }
    // wait for THIS wave's staging only -- no block barrier
    __builtin_amdgcn_s_waitcnt(0x0F70);     // vmcnt(0); lgkm/exp unconstrained
    __builtin_amdgcn_sched_barrier(0);      // pin: no reordering across the wait

    const long long i = waveBox + lane;     // global box index
    if (i >= BN) return;
    const float* L = slw + lane * 25;
    const int n = (int)(i % NBOX);
    const int b = (int)(i / NBOX);

    // decode (identical expression order to reference)
    float4 db = dbox4[n];                   // one coalesced 16B load
    float cy = (db.z + db.x) * 0.5f;
    float cx = (db.w + db.y) * 0.5f;
    float h  = db.z - db.x;
    float w  = db.w - db.y;
    float ncy = L[0] * h + cy;
    float ncx = L[1] * w + cx;
    float nh  = expf(L[2]) * h;
    float nw  = expf(L[3]) * w;
    float y1 = fminf(fmaxf(ncy - nh * 0.5f, 0.f), 1.f);
    float x1 = fminf(fmaxf(ncx - nw * 0.5f, 0.f), 1.f);
    float y2 = fminf(fmaxf(ncy + nh * 0.5f, 0.f), 1.f);
    float x2 = fminf(fmaxf(ncx + nw * 0.5f, 0.f), 1.f);

    // argmax(probs)==argmax(logits), first index on ties;
    // max prob = 1/sum(exp(x-max)), same accumulation order as reference
    float m = L[4];
    int am = 0;
#pragma unroll
    for (int j = 1; j < NCLS; j++) {
        float x = L[4 + j];
        if (x > m) { m = x; am = j; }
    }
    float sum = 0.f;
#pragma unroll
    for (int j = 0; j < NCLS; j++) sum += expf(L[4 + j] - m);
    float score = 1.0f / sum;

    if (am != 0 && score > CONF_THR) {
        int p = atomicAdd(&cnt[b], 1);
        if (p < CAP) {
            float4* c = cand + ((long long)b * CAP + p) * 2;
            c[0] = make_float4(y1, x1, y2, x2);
            c[1] = make_float4(score, (float)am, (float)n, 0.f);
        }
    }
}

// ---------------------------------------------------------------------------
// Phase 2: exact NMS, ONE WAVE per batch element, zero barriers.
// s_sc[i] is read and written only by lane i%64 (single-owner), so no LDS
// cross-lane dependency exists; cross-lane communication is shuffle-only.
// Selection order: (score desc, original index asc) == jnp.argmax semantics.
// Early break on invalid: reference's remaining slots are provably zeros.
// ---------------------------------------------------------------------------
__global__ __launch_bounds__(64) void nms_kernel(
        const float4* __restrict__ cand,
        const int* __restrict__ cnt,
        float* __restrict__ out) {
    const int b    = blockIdx.x;
    const int lane = threadIdx.x;
    __shared__ float s_sc[CAP];
    __shared__ float s_id[CAP];

    const int M = min(cnt[b], CAP);
    const float4* cb = cand + (long long)b * CAP * 2;
    float* o = out + (long long)b * MAXOUT * 6;

    for (int i = lane; i < M; i += 64) {
        float4 mrec = cb[i * 2 + 1];
        s_sc[i] = mrec.x;               // owner: lane i%64 == lane
        s_id[i] = mrec.z;
    }

    int k = 0;
    for (; k < MAXOUT; k++) {
        // per-lane partial argmax over owned slots
        float bv = -INFINITY, boid = 3.0e38f;
        int bi = -1;
        for (int i = lane; i < M; i += 64) {
            float v = s_sc[i], oid = s_id[i];
            if (v > bv || (v == bv && oid < boid)) { bv = v; boid = oid; bi = i; }
        }
        // 64-lane butterfly; all lanes converge to the lexicographic max
        for (int mm = 32; mm >= 1; mm >>= 1) {
            float v2 = __shfl_xor(bv,   mm, 64);
            float o2 = __shfl_xor(boid, mm, 64);
            int   i2 = __shfl_xor(bi,   mm, 64);
            if (v2 > bv || (v2 == bv && o2 < boid)) { bv = v2; boid = o2; bi = i2; }
        }
        if (bi < 0 || !(bv > CONF_THR)) break;   // this & later slots -> zeros

        float4 sb = cb[bi * 2];         // uniform address (scalar-cached)
        if (lane == 0) {
            float4 mm2 = cb[bi * 2 + 1];
            o[k * 6 + 0] = sb.x; o[k * 6 + 1] = sb.y;
            o[k * 6 + 2] = sb.z; o[k * 6 + 3] = sb.w;
            o[k * 6 + 4] = mm2.y; o[k * 6 + 5] = bv;
        }

        // IoU suppression over owned slots (reference formula, includes self)
        float a1 = (sb.z - sb.x) * (sb.w - sb.y);
        for (int i = lane; i < M; i += 64) {
            float4 c = cb[i * 2];
            float tly = fmaxf(sb.x, c.x);
            float tlx = fmaxf(sb.y, c.y);
            float bry = fminf(sb.z, c.z);
            float brx = fminf(sb.w, c.w);
            float wh0 = fmaxf(bry - tly, 0.f);
            float wh1 = fmaxf(brx - tlx, 0.f);
            float inter = wh0 * wh1;
            float a2 = (c.z - c.x) * (c.w - c.y);
            float iou = inter / (a1 + a2 - inter + 1e-12f);
            if (iou > IOU_THR) s_sc[i] = NEG;    // owner-only write
        }
    }
    // zero all remaining slots (d_out is poisoned before every timed launch)
    for (int j = k * 6 + lane; j < MAXOUT * 6; j += 64) o[j] = 0.f;
}

extern "C" void kernel_launch(void* const* d_in, const int* in_sizes, int n_in,
                              void* d_out, int out_size, void* d_ws, size_t ws_size,
                              hipStream_t stream) {
    const float* logits = (const float*)d_in[0];
    const float4* dbox4 = (const float4*)d_in[1];
    float* out          = (float*)d_out;

    const int N  = in_sizes[1] / 4;           // 8732
    const int B  = in_sizes[0] / (N * 25);    // 128
    const int BN = B * N;

    // ws layout: [cnt: B ints][pad to 16B][cand: B*CAP*2 float4]
    int* cnt = (int*)d_ws;
    float4* cand = (float4*)((char*)d_ws + (((size_t)B * sizeof(int) + 15) & ~(size_t)15));

    hipMemsetAsync(cnt, 0, (size_t)B * sizeof(int), stream);
    decode_kernel<<<(BN + 255) / 256, 256, 0, stream>>>(logits, dbox4, cand, cnt, BN);
    nms_kernel<<<B, 64, 0, stream>>>(cand, cnt, out);
}

// Round 8
// 192.888 us; speedup vs baseline: 1.0257x; 1.0097x over previous
//
#include <hip/hip_runtime.h>

#define NEG (-1e9f)
constexpr int NCLS   = 21;
constexpr int NBOX   = 8732;
constexpr int MAXOUT = 5;
constexpr int CAP    = NBOX;          // worst-case candidates per batch
constexpr float IOU_THR  = 0.5f;
constexpr float CONF_THR = 0.5f;

// ---------------------------------------------------------------------------
// Phase 1: decode + softmax max/argmax + candidate compaction.
// R3's proven structure (one-shot, no LDS, no barriers, bit-exact) with the
// occupancy unlocked: 128-thread blocks -> 2183 blocks (~8.5/CU, continuous
// refill) instead of R3's 1092 (4.3/CU, tail-drained at ~12 waves/CU = the
// 37% occupancy ALL of R2-R6 plateaued at). No LDS -> residency bounded only
// by VGPR (~48 < 64 -> 8 waves/SIMD allowed) and WG slots -> up to 32
// waves/CU to cover the ~300-cycle dependent chains + load latency.
// 4 consecutive boxes per thread: 4*25 = 100 floats = 25 aligned float4
// loads (box index g % 4 == 0 -> byte offset g*100 is a multiple of 400).
// Candidate filter: only boxes with (argmax class != 0 && score > CONF_THR)
// can appear in the output (a selection with score <= 0.5 zeroes that slot
// and all later slots, so its suppression never matters).
// Per-box arithmetic identical to reference (bit-exact, absmax 0.0 R1-R5).
// ---------------------------------------------------------------------------
__device__ __forceinline__ void process_box(
        const float* __restrict__ v,   // 25 floats for this box (registers)
        int idx,                        // global box index b*NBOX+n
        const float4* __restrict__ dbox4,
        float4* __restrict__ cand,
        int* __restrict__ cnt) {
    const int n = idx % NBOX;
    const int b = idx / NBOX;

    // decode (identical expression order to reference)
    float4 db = dbox4[n];
    float cy = (db.z + db.x) * 0.5f;
    float cx = (db.w + db.y) * 0.5f;
    float h  = db.z - db.x;
    float w  = db.w - db.y;
    float ncy = v[0] * h + cy;
    float ncx = v[1] * w + cx;
    float nh  = expf(v[2]) * h;
    float nw  = expf(v[3]) * w;
    float y1 = fminf(fmaxf(ncy - nh * 0.5f, 0.f), 1.f);
    float x1 = fminf(fmaxf(ncx - nw * 0.5f, 0.f), 1.f);
    float y2 = fminf(fmaxf(ncy + nh * 0.5f, 0.f), 1.f);
    float x2 = fminf(fmaxf(ncx + nw * 0.5f, 0.f), 1.f);

    // argmax(probs)==argmax(logits), first index on ties;
    // max prob = 1/sum(exp(x-max)), same accumulation order as reference
    float m = v[4];
    int am = 0;
#pragma unroll
    for (int j = 1; j < NCLS; j++) {
        float x = v[4 + j];
        if (x > m) { m = x; am = j; }
    }
    float sum = 0.f;
#pragma unroll
    for (int j = 0; j < NCLS; j++) sum += expf(v[4 + j] - m);
    float score = 1.0f / sum;

    if (am != 0 && score > CONF_THR) {
        int p = atomicAdd(&cnt[b], 1);
        if (p < CAP) {
            float4* c = cand + ((long long)b * CAP + p) * 2;
            c[0] = make_float4(y1, x1, y2, x2);
            c[1] = make_float4(score, (float)am, (float)n, 0.f);
        }
    }
}

__global__ __launch_bounds__(128) void decode_kernel(
        const float* __restrict__ logits,
        const float4* __restrict__ dbox4,
        float4* __restrict__ cand,
        int* __restrict__ cnt,
        int BN) {
    const int g = (blockIdx.x * 128 + threadIdx.x) * 4;
    if (g >= BN) return;

    if (g + 3 < BN) {
        // fast path: 25 aligned float4 loads covering 4 boxes
        const float4* f4 = (const float4*)(logits + (long long)g * 25);
        float v[100];
#pragma unroll
        for (int k = 0; k < 25; k++) {
            float4 r = f4[k];
            v[4 * k + 0] = r.x; v[4 * k + 1] = r.y;
            v[4 * k + 2] = r.z; v[4 * k + 3] = r.w;
        }
#pragma unroll
        for (int j = 0; j < 4; j++)
            process_box(v + 25 * j, g + j, dbox4, cand, cnt);
    } else {
        // tail (only hit if BN % 4 != 0): scalar per-box loads
        for (int j = 0; j < 4 && g + j < BN; j++) {
            const float* L = logits + (long long)(g + j) * 25;
            float v[25];
#pragma unroll
            for (int k = 0; k < 25; k++) v[k] = L[k];
            process_box(v, g + j, dbox4, cand, cnt);
        }
    }
}

// ---------------------------------------------------------------------------
// Phase 2: exact NMS, ONE WAVE per batch element, zero barriers (R5 version,
// passed twice). s_sc[i] is read and written only by lane i%64
// (single-owner); cross-lane communication is shuffle-only. Selection order:
// (score desc, original index asc) == jnp.argmax semantics. Early break:
// remaining slots provably zeros.
// ---------------------------------------------------------------------------
__global__ __launch_bounds__(64) void nms_kernel(
        const float4* __restrict__ cand,
        const int* __restrict__ cnt,
        float* __restrict__ out) {
    const int b    = blockIdx.x;
    const int lane = threadIdx.x;
    __shared__ float s_sc[CAP];
    __shared__ float s_id[CAP];

    const int M = min(cnt[b], CAP);
    const float4* cb = cand + (long long)b * CAP * 2;
    float* o = out + (long long)b * MAXOUT * 6;

    for (int i = lane; i < M; i += 64) {
        float4 mrec = cb[i * 2 + 1];
        s_sc[i] = mrec.x;               // owner: lane i%64 == lane
        s_id[i] = mrec.z;
    }

    int k = 0;
    for (; k < MAXOUT; k++) {
        float bv = -INFINITY, boid = 3.0e38f;
        int bi = -1;
        for (int i = lane; i < M; i += 64) {
            float v = s_sc[i], oid = s_id[i];
            if (v > bv || (v == bv && oid < boid)) { bv = v; boid = oid; bi = i; }
        }
        for (int mm = 32; mm >= 1; mm >>= 1) {
            float v2 = __shfl_xor(bv,   mm, 64);
            float o2 = __shfl_xor(boid, mm, 64);
            int   i2 = __shfl_xor(bi,   mm, 64);
            if (v2 > bv || (v2 == bv && o2 < boid)) { bv = v2; boid = o2; bi = i2; }
        }
        if (bi < 0 || !(bv > CONF_THR)) break;   // this & later slots -> zeros

        float4 sb = cb[bi * 2];
        if (lane == 0) {
            float4 mm2 = cb[bi * 2 + 1];
            o[k * 6 + 0] = sb.x; o[k * 6 + 1] = sb.y;
            o[k * 6 + 2] = sb.z; o[k * 6 + 3] = sb.w;
            o[k * 6 + 4] = mm2.y; o[k * 6 + 5] = bv;
        }

        float a1 = (sb.z - sb.x) * (sb.w - sb.y);
        for (int i = lane; i < M; i += 64) {
            float4 c = cb[i * 2];
            float tly = fmaxf(sb.x, c.x);
            float tlx = fmaxf(sb.y, c.y);
            float bry = fminf(sb.z, c.z);
            float brx = fminf(sb.w, c.w);
            float wh0 = fmaxf(bry - tly, 0.f);
            float wh1 = fmaxf(brx - tlx, 0.f);
            float inter = wh0 * wh1;
            float a2 = (c.z - c.x) * (c.w - c.y);
            float iou = inter / (a1 + a2 - inter + 1e-12f);
            if (iou > IOU_THR) s_sc[i] = NEG;    // owner-only write
        }
    }
    for (int j = k * 6 + lane; j < MAXOUT * 6; j += 64) o[j] = 0.f;
}

extern "C" void kernel_launch(void* const* d_in, const int* in_sizes, int n_in,
                              void* d_out, int out_size, void* d_ws, size_t ws_size,
                              hipStream_t stream) {
    const float* logits = (const float*)d_in[0];
    const float4* dbox4 = (const float4*)d_in[1];
    float* out          = (float*)d_out;

    const int N  = in_sizes[1] / 4;           // 8732
    const int B  = in_sizes[0] / (N * 25);    // 128
    const int BN = B * N;

    // ws layout: [cnt: B ints][pad to 16B][cand: B*CAP*2 float4]
    int* cnt = (int*)d_ws;
    float4* cand = (float4*)((char*)d_ws + (((size_t)B * sizeof(int) + 15) & ~(size_t)15));

    hipMemsetAsync(cnt, 0, (size_t)B * sizeof(int), stream);
    const int nthreads = (BN + 3) / 4;
    decode_kernel<<<(nthreads + 127) / 128, 128, 0, stream>>>(logits, dbox4, cand, cnt, BN);
    nms_kernel<<<B, 64, 0, stream>>>(cand, cnt, out);
}